// Round 1
// baseline (2875.425 us; speedup 1.0000x reference)
//
#include <hip/hip_runtime.h>
#include <math.h>

#define NLAYERS 4
#define HDIM 1024
#define NSTATE 32
#define BATCH 8
#define SEQ 1024

static __device__ __forceinline__ float sigmoidf_(float x) {
  return 1.0f / (1.0f + expf(-x));
}
static __device__ __forceinline__ float geluf_(float x) {
  // jax.nn.gelu default (approximate=True): tanh approximation
  float t = 0.7978845608028654f * fmaf(0.044715f, x * x * x, x);
  return 0.5f * x * (1.0f + tanhf(t));
}

// x (B,L,H) -> h (B,H,L)
__global__ __launch_bounds__(256) void k_transpose_in(const float* __restrict__ x,
                                                      float* __restrict__ h) {
  __shared__ float t[64][65];
  const int b = blockIdx.z;
  const int h0 = blockIdx.x * 64;
  const int l0 = blockIdx.y * 64;
  const int c = threadIdx.x & 63;
  const int r0 = threadIdx.x >> 6;
  const float* xp = x + (size_t)b * SEQ * HDIM;
#pragma unroll
  for (int r = r0; r < 64; r += 4)
    t[r][c] = xp[(size_t)(l0 + r) * HDIM + h0 + c];
  __syncthreads();
  float* hp = h + (size_t)b * HDIM * SEQ;
#pragma unroll
  for (int r = r0; r < 64; r += 4)
    hp[(size_t)(h0 + r) * SEQ + l0 + c] = t[c][r];
}

// h (B,H,L) -> out (B,L,H)
__global__ __launch_bounds__(256) void k_transpose_out(const float* __restrict__ h,
                                                       float* __restrict__ o) {
  __shared__ float t[64][65];
  const int b = blockIdx.z;
  const int h0 = blockIdx.x * 64;
  const int l0 = blockIdx.y * 64;
  const int c = threadIdx.x & 63;
  const int r0 = threadIdx.x >> 6;
  const float* hp = h + (size_t)b * HDIM * SEQ;
#pragma unroll
  for (int r = r0; r < 64; r += 4)
    t[r][c] = hp[(size_t)(h0 + r) * SEQ + l0 + c];
  __syncthreads();
  float* op = o + (size_t)b * SEQ * HDIM;
#pragma unroll
  for (int r = r0; r < 64; r += 4)
    op[(size_t)(l0 + r) * HDIM + h0 + c] = t[c][r];
}

// channel LayerNorm over H at each (b,l); h,z in (B,H,L)
__global__ __launch_bounds__(256) void k_ln(const float* __restrict__ h,
                                            float* __restrict__ z,
                                            const float* __restrict__ w,
                                            const float* __restrict__ bb) {
  __shared__ float ps[8][32], ps2[8][32], smu[32], srs[32];
  const int t = threadIdx.x;
  const int hc = t >> 5;          // 0..7 channel-chunk
  const int li = t & 31;          // l within block
  const int p0 = blockIdx.x * 32; // global (b*SEQ + l) base
  const int b = p0 >> 10;
  const int l = (p0 & (SEQ - 1)) + li;
  const float* hp = h + (size_t)b * HDIM * SEQ + l;
  float s = 0.f, s2 = 0.f;
  const int h0 = hc * 128;
#pragma unroll 8
  for (int i = 0; i < 128; ++i) {
    float v = hp[(size_t)(h0 + i) * SEQ];
    s += v;
    s2 = fmaf(v, v, s2);
  }
  ps[hc][li] = s;
  ps2[hc][li] = s2;
  __syncthreads();
  if (t < 32) {
    float ss = 0.f, ss2 = 0.f;
#pragma unroll
    for (int c = 0; c < 8; ++c) { ss += ps[c][t]; ss2 += ps2[c][t]; }
    float mu = ss * (1.0f / HDIM);
    float var = ss2 * (1.0f / HDIM) - mu * mu;
    smu[t] = mu;
    srs[t] = 1.0f / sqrtf(var + 1e-5f);
  }
  __syncthreads();
  const float mu = smu[li], rs = srs[li];
  float* zp = z + (size_t)b * HDIM * SEQ + l;
#pragma unroll 8
  for (int i = 0; i < 128; ++i) {
    const int hh = h0 + i;
    float v = hp[(size_t)hh * SEQ];
    zp[(size_t)hh * SEQ] = fmaf((v - mu) * rs, w[hh], bb[hh]);
  }
}

// Diagonal SSM recurrence (exact equivalent of Vandermonde-kernel causal conv),
// fused with D_skip and GELU. In-place on z (B,H,L).
// 32 lanes per (b,h): lane = state n. 8 (b,h) pairs per 256-thread block.
__global__ __launch_bounds__(256) void k_scan(float* __restrict__ z,
    const float* __restrict__ log_dt, const float* __restrict__ A_re_log,
    const float* __restrict__ A_im, const float* __restrict__ C_re,
    const float* __restrict__ C_im, const float* __restrict__ D_skip) {
  const int t = threadIdx.x;
  const int g = t >> 5;                  // group 0..7
  const int lane = t & 31;               // state index n
  const int pair = blockIdx.x * 8 + g;
  const int b = pair >> 10;              // pair / HDIM
  const int hh = pair & (HDIM - 1);
  const float dt = expf(log_dt[hh]);
  const int idx = hh * NSTATE + lane;
  const float Are = -expf(A_re_log[idx]);
  const float Aim = A_im[idx];
  const float dre = Are * dt, dim = Aim * dt;
  const float cy = cosf(dim), sy = sinf(dim);
  const float em = expm1f(dre);
  const float ex = em + 1.0f;            // exp(dre)
  const float er = ex * cy, ei = ex * sy;              // decay e = exp(dtA)
  const float em1r = fmaf(em, cy, cy - 1.0f);          // Re(expm1(dtA))
  const float em1i = ei;                                // Im(expm1(dtA))
  const float den = 1.0f / fmaf(Are, Are, Aim * Aim);
  const float rr = (em1r * Are + em1i * Aim) * den;    // expm1(dtA)/A
  const float ri = (em1i * Are - em1r * Aim) * den;
  const float cr = C_re[idx], ci = C_im[idx];
  const float Ctr = 2.0f * (cr * rr - ci * ri);        // 2*C~ (factor 2 folded)
  const float Cti = 2.0f * (cr * ri + ci * rr);
  const float D = D_skip[hh];
  float* zp = z + (size_t)b * HDIM * SEQ + (size_t)hh * SEQ;
  float sr = 0.f, si = 0.f;
  for (int l0 = 0; l0 < SEQ; l0 += 32) {
    const float zv = zp[l0 + lane];      // coalesced chunk load
    float yv = 0.f;
#pragma unroll
    for (int j = 0; j < 32; ++j) {
      const float zj = __shfl(zv, j, 32);
      const float nr = fmaf(er, sr, fmaf(-ei, si, zj));
      const float ni = fmaf(er, si, ei * sr);
      sr = nr;
      si = ni;
      float p = fmaf(Ctr, sr, -(Cti * si));
#pragma unroll
      for (int off = 16; off > 0; off >>= 1)
        p += __shfl_xor(p, off, 32);
      if (lane == j) yv = p;             // keep y[l0+lane] in its lane
    }
    zp[l0 + lane] = geluf_(fmaf(D, zv, yv));
  }
}

// out = W(2H,H) @ y(B,H,L); GLU(out[:H], out[H:]) added into residual h.
// 128x128 tile, BK=16, 256 threads, per-thread 2x8x8 f32 accumulators.
__global__ __launch_bounds__(256, 2) void k_gemm_glu(
    const float* __restrict__ y, const float* __restrict__ W,
    const float* __restrict__ bias, float* __restrict__ h) {
  __shared__ float Wlt[2][16][128];   // [half][k][m], k-major for b128 reads
  __shared__ float Yl[16][128];       // [k][n]
  const int b = blockIdx.z;
  const int om0 = blockIdx.y * 128;
  const int l0 = blockIdx.x * 128;
  const int t = threadIdx.x;
  const int tx = t & 15, ty = t >> 4;
  const float* yp = y + (size_t)b * HDIM * SEQ;

  float acc0[8][8], acc1[8][8];
#pragma unroll
  for (int i = 0; i < 8; ++i)
#pragma unroll
    for (int j = 0; j < 8; ++j) { acc0[i][j] = 0.f; acc1[i][j] = 0.f; }

  const int wr = t & 127;         // W row within tile
  const int wc4 = (t >> 7) * 4;   // 0 or 4 (k sub-chunk)
  const int yr = t >> 5;          // 0..7
  const int yc = (t & 31) * 4;

  for (int k0 = 0; k0 < HDIM; k0 += 16) {
    const float4 yv0 = *(const float4*)&yp[(size_t)(k0 + yr) * SEQ + l0 + yc];
    const float4 yv1 = *(const float4*)&yp[(size_t)(k0 + yr + 8) * SEQ + l0 + yc];
    const float4 w00 = *(const float4*)&W[(size_t)(om0 + wr) * HDIM + k0 + wc4];
    const float4 w01 = *(const float4*)&W[(size_t)(om0 + wr) * HDIM + k0 + 8 + wc4];
    const float4 w10 = *(const float4*)&W[(size_t)(om0 + wr + HDIM) * HDIM + k0 + wc4];
    const float4 w11 = *(const float4*)&W[(size_t)(om0 + wr + HDIM) * HDIM + k0 + 8 + wc4];
    __syncthreads();
    *(float4*)&Yl[yr][yc] = yv0;
    *(float4*)&Yl[yr + 8][yc] = yv1;
    Wlt[0][wc4 + 0][wr] = w00.x; Wlt[0][wc4 + 1][wr] = w00.y;
    Wlt[0][wc4 + 2][wr] = w00.z; Wlt[0][wc4 + 3][wr] = w00.w;
    Wlt[0][wc4 + 8][wr] = w01.x; Wlt[0][wc4 + 9][wr] = w01.y;
    Wlt[0][wc4 + 10][wr] = w01.z; Wlt[0][wc4 + 11][wr] = w01.w;
    Wlt[1][wc4 + 0][wr] = w10.x; Wlt[1][wc4 + 1][wr] = w10.y;
    Wlt[1][wc4 + 2][wr] = w10.z; Wlt[1][wc4 + 3][wr] = w10.w;
    Wlt[1][wc4 + 8][wr] = w11.x; Wlt[1][wc4 + 9][wr] = w11.y;
    Wlt[1][wc4 + 10][wr] = w11.z; Wlt[1][wc4 + 11][wr] = w11.w;
    __syncthreads();
#pragma unroll
    for (int k = 0; k < 16; ++k) {
      const float4 ya = *(const float4*)&Yl[k][tx * 4];
      const float4 yb = *(const float4*)&Yl[k][64 + tx * 4];
      const float4 a0a = *(const float4*)&Wlt[0][k][ty * 4];
      const float4 a0b = *(const float4*)&Wlt[0][k][64 + ty * 4];
      const float4 a1a = *(const float4*)&Wlt[1][k][ty * 4];
      const float4 a1b = *(const float4*)&Wlt[1][k][64 + ty * 4];
      const float A0[8] = {a0a.x, a0a.y, a0a.z, a0a.w, a0b.x, a0b.y, a0b.z, a0b.w};
      const float A1[8] = {a1a.x, a1a.y, a1a.z, a1a.w, a1b.x, a1b.y, a1b.z, a1b.w};
      const float Yv[8] = {ya.x, ya.y, ya.z, ya.w, yb.x, yb.y, yb.z, yb.w};
#pragma unroll
      for (int i = 0; i < 8; ++i)
#pragma unroll
        for (int j = 0; j < 8; ++j) {
          acc0[i][j] = fmaf(A0[i], Yv[j], acc0[i][j]);
          acc1[i][j] = fmaf(A1[i], Yv[j], acc1[i][j]);
        }
    }
  }
  float* hp = h + (size_t)b * HDIM * SEQ;
#pragma unroll
  for (int i = 0; i < 8; ++i) {
    const int m = (i < 4) ? (ty * 4 + i) : (64 + ty * 4 + (i - 4));
    const int o = om0 + m;
    const float b0 = bias[o];
    const float b1 = bias[o + HDIM];
#pragma unroll
    for (int jg = 0; jg < 2; ++jg) {
      const size_t off = (size_t)o * SEQ + l0 + jg * 64 + tx * 4;
      float4 hv = *(float4*)&hp[off];
      float r[4] = {hv.x, hv.y, hv.z, hv.w};
#pragma unroll
      for (int j4 = 0; j4 < 4; ++j4) {
        const float u0 = acc0[i][jg * 4 + j4] + b0;
        const float u1 = acc1[i][jg * 4 + j4] + b1;
        r[j4] = fmaf(u0, sigmoidf_(u1), r[j4]);   // residual += GLU
      }
      hv.x = r[0]; hv.y = r[1]; hv.z = r[2]; hv.w = r[3];
      *(float4*)&hp[off] = hv;
    }
  }
}

extern "C" void kernel_launch(void* const* d_in, const int* in_sizes, int n_in,
                              void* d_out, int out_size, void* d_ws, size_t ws_size,
                              hipStream_t stream) {
  (void)in_sizes; (void)n_in; (void)out_size; (void)ws_size;
  const float* x        = (const float*)d_in[0];
  const float* ln_w     = (const float*)d_in[1];
  const float* ln_b     = (const float*)d_in[2];
  const float* log_dt   = (const float*)d_in[3];
  const float* A_re_log = (const float*)d_in[4];
  const float* A_im     = (const float*)d_in[5];
  const float* C_re     = (const float*)d_in[6];
  const float* C_im     = (const float*)d_in[7];
  const float* D_skip   = (const float*)d_in[8];
  const float* W_out    = (const float*)d_in[9];
  const float* b_out    = (const float*)d_in[10];
  float* out = (float*)d_out;
  // workspace: h residual (B,H,L) + z activations (B,H,L) = 64 MB
  float* h = (float*)d_ws;
  float* z = h + (size_t)BATCH * HDIM * SEQ;

  k_transpose_in<<<dim3(HDIM / 64, SEQ / 64, BATCH), 256, 0, stream>>>(x, h);
  for (int i = 0; i < NLAYERS; ++i) {
    k_ln<<<BATCH * SEQ / 32, 256, 0, stream>>>(h, z, ln_w + i * HDIM, ln_b + i * HDIM);
    k_scan<<<BATCH * HDIM / 8, 256, 0, stream>>>(z, log_dt + i * HDIM,
        A_re_log + i * HDIM * NSTATE, A_im + i * HDIM * NSTATE,
        C_re + i * HDIM * NSTATE, C_im + i * HDIM * NSTATE, D_skip + i * HDIM);
    k_gemm_glu<<<dim3(SEQ / 128, HDIM / 128, BATCH), 256, 0, stream>>>(
        z, W_out + (size_t)i * 2 * HDIM * HDIM, b_out + (size_t)i * 2 * HDIM, h);
  }
  k_transpose_out<<<dim3(HDIM / 64, SEQ / 64, BATCH), 256, 0, stream>>>(h, out);
}

// Round 3
// 1194.811 us; speedup vs baseline: 2.4066x; 2.4066x over previous
//
#include <hip/hip_runtime.h>
#include <math.h>

#define NLAYERS 4
#define HDIM 1024
#define NSTATE 32
#define BATCH 8
#define SEQ 1024

typedef unsigned short u16;
typedef unsigned int u32;
typedef __attribute__((ext_vector_type(8))) short short8;
typedef __attribute__((ext_vector_type(4))) float f32x4;

#define GAS __attribute__((address_space(1)))
#define LAS __attribute__((address_space(3)))

static __device__ __forceinline__ void gload16(const void* g, u16* l) {
  __builtin_amdgcn_global_load_lds((const GAS u32*)g, (LAS u32*)l, 16, 0, 0);
}

static __device__ __forceinline__ u16 f2bf(float f) {
  u32 u = __float_as_uint(f);
  return (u16)((u + 0x7fffu + ((u >> 16) & 1u)) >> 16);
}
static __device__ __forceinline__ float bf2f(u16 h) {
  return __uint_as_float((u32)h << 16);
}
static __device__ __forceinline__ float sigmoid_(float x) {
  return 1.0f / (1.0f + __expf(-x));
}
static __device__ __forceinline__ float gelu_(float x) {
  // jax.nn.gelu tanh-approx: x*sigmoid(2*0.79788456*(x+0.044715x^3))
  const float t3 = x * x * x;
  return x / (1.0f + __expf(-1.5957691216057308f * fmaf(0.044715f, t3, x)));
}

// x (B,L,H) -> h (B,H,L)
__global__ __launch_bounds__(256) void k_transpose_in(const float* __restrict__ x,
                                                      float* __restrict__ h) {
  __shared__ float t[64][65];
  const int b = blockIdx.z;
  const int h0 = blockIdx.x * 64;
  const int l0 = blockIdx.y * 64;
  const int c = threadIdx.x & 63;
  const int r0 = threadIdx.x >> 6;
  const float* xp = x + (size_t)b * SEQ * HDIM;
#pragma unroll
  for (int r = r0; r < 64; r += 4)
    t[r][c] = xp[(size_t)(l0 + r) * HDIM + h0 + c];
  __syncthreads();
  float* hp = h + (size_t)b * HDIM * SEQ;
#pragma unroll
  for (int r = r0; r < 64; r += 4)
    hp[(size_t)(h0 + r) * SEQ + l0 + c] = t[c][r];
}

// h (B,H,L) -> out (B,L,H)
__global__ __launch_bounds__(256) void k_transpose_out(const float* __restrict__ h,
                                                       float* __restrict__ o) {
  __shared__ float t[64][65];
  const int b = blockIdx.z;
  const int h0 = blockIdx.x * 64;
  const int l0 = blockIdx.y * 64;
  const int c = threadIdx.x & 63;
  const int r0 = threadIdx.x >> 6;
  const float* hp = h + (size_t)b * HDIM * SEQ;
#pragma unroll
  for (int r = r0; r < 64; r += 4)
    t[r][c] = hp[(size_t)(h0 + r) * SEQ + l0 + c];
  __syncthreads();
  float* op = o + (size_t)b * SEQ * HDIM;
#pragma unroll
  for (int r = r0; r < 64; r += 4)
    op[(size_t)(l0 + r) * HDIM + h0 + c] = t[c][r];
}

// channel LayerNorm over H at each (b,l); h,z in (B,H,L)
__global__ __launch_bounds__(256) void k_ln(const float* __restrict__ h,
                                            float* __restrict__ z,
                                            const float* __restrict__ w,
                                            const float* __restrict__ bb) {
  __shared__ float ps[8][32], ps2[8][32], smu[32], srs[32];
  const int t = threadIdx.x;
  const int hc = t >> 5;
  const int li = t & 31;
  const int p0 = blockIdx.x * 32;
  const int b = p0 >> 10;
  const int l = (p0 & (SEQ - 1)) + li;
  const float* hp = h + (size_t)b * HDIM * SEQ + l;
  float s = 0.f, s2 = 0.f;
  const int h0 = hc * 128;
#pragma unroll 8
  for (int i = 0; i < 128; ++i) {
    float v = hp[(size_t)(h0 + i) * SEQ];
    s += v;
    s2 = fmaf(v, v, s2);
  }
  ps[hc][li] = s;
  ps2[hc][li] = s2;
  __syncthreads();
  if (t < 32) {
    float ss = 0.f, ss2 = 0.f;
#pragma unroll
    for (int c = 0; c < 8; ++c) { ss += ps[c][t]; ss2 += ps2[c][t]; }
    float mu = ss * (1.0f / HDIM);
    float var = ss2 * (1.0f / HDIM) - mu * mu;
    smu[t] = mu;
    srs[t] = 1.0f / sqrtf(var + 1e-5f);
  }
  __syncthreads();
  const float mu = smu[li], rs = srs[li];
  float* zp = z + (size_t)b * HDIM * SEQ + l;
#pragma unroll 8
  for (int i = 0; i < 128; ++i) {
    const int hh = h0 + i;
    float v = hp[(size_t)hh * SEQ];
    zp[(size_t)hh * SEQ] = fmaf((v - mu) * rs, w[hh], bb[hh]);
  }
}

// Chunked diagonal-SSM scan + D_skip + GELU, emitting y as split-bf16 in
// (B, L, H) layout. Group of 32 lanes per (b,h); lane = 32-step chunk of L.
// Local recurrence -> Kogge-Stone complex prefix scan of chunk states ->
// final recurrence with correct init. Block covers 8 consecutive h of one b;
// LDS transpose gives one uint4 (8 h) store per l for hi and lo.
__global__ __launch_bounds__(256) void k_scan(
    const float* __restrict__ z, u16* __restrict__ yhi, u16* __restrict__ ylo,
    const float* __restrict__ log_dt, const float* __restrict__ A_re_log,
    const float* __restrict__ A_im, const float* __restrict__ C_re,
    const float* __restrict__ C_im, const float* __restrict__ D_skip) {
  __shared__ float4 prm[8][32];
  __shared__ float2 p32[8][32];
  __shared__ u32 ybuf[8][1028];
  const int t = threadIdx.x;
  const int g = t >> 5, lane = t & 31;
  const int pair = blockIdx.x * 8 + g;
  const int b = pair >> 10, hh = pair & (HDIM - 1);
  {
    const float dt = expf(log_dt[hh]);
    const int idx = hh * NSTATE + lane;
    const float Are = -expf(A_re_log[idx]);
    const float Aim = A_im[idx];
    const float dre = Are * dt, dim = Aim * dt;
    const float cy = cosf(dim), sy = sinf(dim);
    const float em = expm1f(dre);
    const float ex = em + 1.0f;
    const float er = ex * cy, ei = ex * sy;           // exp(dtA)
    const float em1r = fmaf(em, cy, cy - 1.0f);       // Re expm1(dtA)
    const float em1i = ei;                            // Im expm1(dtA)
    const float den = 1.0f / fmaf(Are, Are, Aim * Aim);
    const float rr = (em1r * Are + em1i * Aim) * den; // expm1(dtA)/A
    const float ri = (em1i * Are - em1r * Aim) * den;
    const float cr = C_re[idx], ci = C_im[idx];
    prm[g][lane] = make_float4(er, ei, 2.0f * (cr * rr - ci * ri),
                               2.0f * (cr * ri + ci * rr));
    float ar = er, ai = ei;                           // e^32 via 5 squarings
#pragma unroll
    for (int q = 0; q < 5; ++q) {
      const float nr = fmaf(ar, ar, -(ai * ai));
      ai = 2.0f * ar * ai;
      ar = nr;
    }
    p32[g][lane] = make_float2(ar, ai);
  }
  __syncthreads();
  const float* zp = z + ((size_t)b * HDIM + hh) * SEQ + lane * 32;
  float zb[32];
#pragma unroll
  for (int i = 0; i < 8; ++i) {
    const float4 v = *(const float4*)(zp + i * 4);
    zb[i * 4] = v.x; zb[i * 4 + 1] = v.y; zb[i * 4 + 2] = v.z; zb[i * 4 + 3] = v.w;
  }
  float ya[32];
#pragma unroll
  for (int j = 0; j < 32; ++j) ya[j] = 0.f;
  for (int n = 0; n < NSTATE; ++n) {
    const float4 pp = prm[g][n];
    const float er = pp.x, ei = pp.y, Ctr = pp.z, Cti = pp.w;
    const float2 q32 = p32[g][n];
    float sr = 0.f, si = 0.f;
#pragma unroll
    for (int j = 0; j < 32; ++j) {   // local pass (chunk state only)
      const float nr = fmaf(er, sr, fmaf(-ei, si, zb[j]));
      si = fmaf(er, si, ei * sr);
      sr = nr;
    }
    float fr = q32.x, fi = q32.y;    // inclusive Kogge-Stone scan, ratio e^32
#pragma unroll
    for (int d = 1; d < 32; d <<= 1) {
      const float ur = __shfl_up(sr, d, 32);
      const float ui = __shfl_up(si, d, 32);
      if (lane >= d) {
        sr = fmaf(fr, ur, fmaf(-fi, ui, sr));
        si = fmaf(fr, ui, fmaf(fi, ur, si));
      }
      const float nfr = fmaf(fr, fr, -(fi * fi));
      fi = 2.0f * fr * fi;
      fr = nfr;
    }
    float inr = __shfl_up(sr, 1, 32); // exclusive = state entering this chunk
    float ini = __shfl_up(si, 1, 32);
    if (lane == 0) { inr = 0.f; ini = 0.f; }
    sr = inr; si = ini;
#pragma unroll
    for (int j = 0; j < 32; ++j) {   // final pass with correct init + y accum
      const float nr = fmaf(er, sr, fmaf(-ei, si, zb[j]));
      si = fmaf(er, si, ei * sr);
      sr = nr;
      ya[j] = fmaf(Ctr, sr, fmaf(-Cti, si, ya[j]));
    }
  }
  const float D = D_skip[hh];
  // pack hi|lo u32, stage with bit-swapped index (conflict-free writes)
#pragma unroll
  for (int j = 0; j < 32; ++j) {
    const float yv = gelu_(fmaf(D, zb[j], ya[j]));
    const u16 hi = f2bf(yv);
    const u16 lo = f2bf(yv - bf2f(hi));
    ybuf[g][(j << 5) | lane] = (u32)hi | ((u32)lo << 16);
  }
  __syncthreads();
  const int b2 = (blockIdx.x * 8) >> 10;
  const int h0 = (blockIdx.x * 8) & (HDIM - 1);
#pragma unroll
  for (int q = 0; q < 4; ++q) {
    const int l = ((t & 31) << 5) + (t >> 5) + 8 * q;
    const int idx = (((t >> 5) + 8 * q) << 5) | (t & 31);
    u32 v[8];
#pragma unroll
    for (int g2 = 0; g2 < 8; ++g2) v[g2] = ybuf[g2][idx];
    uint4 HI, LO;
    HI.x = (v[0] & 0xffffu) | (v[1] << 16);
    HI.y = (v[2] & 0xffffu) | (v[3] << 16);
    HI.z = (v[4] & 0xffffu) | (v[5] << 16);
    HI.w = (v[6] & 0xffffu) | (v[7] << 16);
    LO.x = (v[0] >> 16) | (v[1] & 0xffff0000u);
    LO.y = (v[2] >> 16) | (v[3] & 0xffff0000u);
    LO.z = (v[4] >> 16) | (v[5] & 0xffff0000u);
    LO.w = (v[6] >> 16) | (v[7] & 0xffff0000u);
    const size_t base = ((size_t)b2 * SEQ + l) * HDIM + h0;
    *(uint4*)(yhi + base) = HI;
    *(uint4*)(ylo + base) = LO;
  }
}

// W (2H,H) f32 -> bf16 hi + bf16 residual lo
__global__ __launch_bounds__(256) void k_wsplit(const float* __restrict__ W,
                                                u16* __restrict__ whi,
                                                u16* __restrict__ wlo) {
  const size_t i = ((size_t)blockIdx.x * 256 + threadIdx.x) * 4;
  const float4 v = *(const float4*)(W + i);
  const float f[4] = {v.x, v.y, v.z, v.w};
  u32 hp[2], lp[2];
#pragma unroll
  for (int q = 0; q < 2; ++q) {
    const u16 h0 = f2bf(f[q * 2]), h1 = f2bf(f[q * 2 + 1]);
    const u16 l0 = f2bf(f[q * 2] - bf2f(h0)), l1 = f2bf(f[q * 2 + 1] - bf2f(h1));
    hp[q] = (u32)h0 | ((u32)h1 << 16);
    lp[q] = (u32)l0 | ((u32)l1 << 16);
  }
  *(uint2*)(whi + i) = make_uint2(hp[0], hp[1]);
  *(uint2*)(wlo + i) = make_uint2(lp[0], lp[1]);
}

// out = W(2H,H) @ y^T; y in (B,L,H) so BOTH operands stage as [row][32k] and
// read as contiguous short8 (m97-verified pattern; no transpose reads).
// GLU(out[:H], out[H:]) added into residual h (B,H,L). 128x128 tile, BK=32,
// 4 waves. A rows interleave the GLU halves in 32-row blocks so acc[m] (u0)
// pairs with acc[m+2] (u1) thread-locally.
__global__ __launch_bounds__(256) void k_gemm_glu(
    const u16* __restrict__ yhi, const u16* __restrict__ ylo,
    const u16* __restrict__ whi, const u16* __restrict__ wlo,
    const float* __restrict__ bias, float* __restrict__ h) {
  __shared__ __align__(16) u16 smem[8192];  // A: [0,4096) 128r x 32k; B: [4096,8192) 128l x 32k
  const int tid = threadIdx.x;
  const int bb = blockIdx.z;
  const int my = blockIdx.y;
  const int l0 = blockIdx.x * 128;
  const int lane = tid & 63, wid = tid >> 6;
  const int wr = wid & 1, wc = wid >> 1;
  const int l15 = lane & 15, g4 = lane >> 4;

  f32x4 acc[4][4];
#pragma unroll
  for (int m = 0; m < 4; ++m)
#pragma unroll
    for (int n = 0; n < 4; ++n) acc[m][n] = (f32x4){0.f, 0.f, 0.f, 0.f};

  size_t aOff[2], bOff[2];
#pragma unroll
  for (int i = 0; i < 2; ++i) {
    const int CH = tid + 256 * i;
    const int row = CH >> 2, ko = (CH & 3) * 8;  // LDS [row][32k], 16B = 8 k
    // A: interleave halves in 32-row blocks: LDS rows 0..31 -> u0 rows 0..31,
    // 32..63 -> u1 rows 0..31, 64..95 -> u0 32..63, 96..127 -> u1 32..63
    const int gg = row >> 5, rr = row & 31;
    const int grow = (gg & 1) * HDIM + my * 64 + (gg >> 1) * 32 + rr;
    aOff[i] = (size_t)grow * HDIM + ko;
    // B: y (B,L,H): LDS l-row <- global l0+row, k contiguous
    bOff[i] = ((size_t)(bb * SEQ + l0 + row)) * HDIM + ko;
  }
  u16* aDst0 = &smem[wid * 512];
  u16* aDst1 = &smem[wid * 512 + 2048];
  u16* bDst0 = &smem[4096 + wid * 512];
  u16* bDst1 = &smem[4096 + wid * 512 + 2048];

#pragma unroll 1
  for (int p = 0; p < 3; ++p) {
    const u16* Wp = (p == 2) ? wlo : whi;
    const u16* Yp = (p == 1) ? ylo : yhi;
#pragma unroll 1
    for (int k0 = 0; k0 < HDIM; k0 += 32) {
      __syncthreads();
      gload16(Wp + aOff[0] + k0, aDst0);
      gload16(Wp + aOff[1] + k0, aDst1);
      gload16(Yp + bOff[0] + k0, bDst0);
      gload16(Yp + bOff[1] + k0, bDst1);
      __syncthreads();
      short8 a[4], bq[4];
#pragma unroll
      for (int m = 0; m < 4; ++m)
        a[m] = *(const short8*)&smem[(wr * 64 + m * 16 + l15) * 32 + g4 * 8];
#pragma unroll
      for (int n = 0; n < 4; ++n)
        bq[n] = *(const short8*)&smem[4096 + (wc * 64 + n * 16 + l15) * 32 + g4 * 8];
#pragma unroll
      for (int m = 0; m < 4; ++m)
#pragma unroll
        for (int n = 0; n < 4; ++n)
          acc[m][n] =
              __builtin_amdgcn_mfma_f32_16x16x32_bf16(a[m], bq[n], acc[m][n], 0, 0, 0);
    }
  }

  float* hp = h + (size_t)bb * HDIM * SEQ;
#pragma unroll
  for (int m = 0; m < 2; ++m)
#pragma unroll
    for (int j = 0; j < 4; ++j) {
      const int R = my * 64 + wr * 32 + m * 16 + g4 * 4 + j;
      const float b0 = bias[R], b1 = bias[HDIM + R];
#pragma unroll
      for (int n = 0; n < 4; ++n) {
        const float u0 = acc[m][n][j] + b0;
        const float u1 = acc[m + 2][n][j] + b1;
        const int c = l0 + wc * 64 + n * 16 + l15;
        hp[(size_t)R * SEQ + c] += u0 * sigmoid_(u1);
      }
    }
}

extern "C" void kernel_launch(void* const* d_in, const int* in_sizes, int n_in,
                              void* d_out, int out_size, void* d_ws, size_t ws_size,
                              hipStream_t stream) {
  (void)in_sizes; (void)n_in; (void)out_size; (void)ws_size;
  const float* x        = (const float*)d_in[0];
  const float* ln_w     = (const float*)d_in[1];
  const float* ln_b     = (const float*)d_in[2];
  const float* log_dt   = (const float*)d_in[3];
  const float* A_re_log = (const float*)d_in[4];
  const float* A_im     = (const float*)d_in[5];
  const float* C_re     = (const float*)d_in[6];
  const float* C_im     = (const float*)d_in[7];
  const float* D_skip   = (const float*)d_in[8];
  const float* W_out    = (const float*)d_in[9];
  const float* b_out    = (const float*)d_in[10];

  const size_t NTOK = (size_t)BATCH * HDIM * SEQ;  // 8M
  float* h = (float*)d_ws;                         // 32MB
  float* z = h + NTOK;                             // 32MB (reused as W-split)
  u16* whi = (u16*)z;                              // overlays z after scan
  u16* wlo = whi + (size_t)2 * HDIM * HDIM;
  u16* yhi = (u16*)d_out;                          // d_out doubles as y buffer
  u16* ylo = yhi + NTOK;

  k_transpose_in<<<dim3(HDIM / 64, SEQ / 64, BATCH), 256, 0, stream>>>(x, h);
  for (int i = 0; i < NLAYERS; ++i) {
    k_ln<<<BATCH * SEQ / 32, 256, 0, stream>>>(h, z, ln_w + i * HDIM, ln_b + i * HDIM);
    k_scan<<<BATCH * HDIM / 8, 256, 0, stream>>>(z, yhi, ylo, log_dt + i * HDIM,
        A_re_log + (size_t)i * HDIM * NSTATE, A_im + (size_t)i * HDIM * NSTATE,
        C_re + (size_t)i * HDIM * NSTATE, C_im + (size_t)i * HDIM * NSTATE,
        D_skip + i * HDIM);
    k_wsplit<<<2 * HDIM * HDIM / 1024, 256, 0, stream>>>(
        W_out + (size_t)i * 2 * HDIM * HDIM, whi, wlo);
    k_gemm_glu<<<dim3(SEQ / 128, HDIM / 64, BATCH), 256, 0, stream>>>(
        yhi, ylo, whi, wlo, b_out + (size_t)i * 2 * HDIM, h);
  }
  k_transpose_out<<<dim3(HDIM / 64, SEQ / 64, BATCH), 256, 0, stream>>>(h, (float*)d_out);
}

// Round 4
// 839.754 us; speedup vs baseline: 3.4241x; 1.4228x over previous
//
#include <hip/hip_runtime.h>
#include <math.h>

#define NLAYERS 4
#define HDIM 1024
#define NSTATE 32
#define BATCH 8
#define SEQ 1024

typedef unsigned short u16;
typedef unsigned int u32;
typedef __attribute__((ext_vector_type(8))) short short8;
typedef __attribute__((ext_vector_type(4))) float f32x4;

#define GAS __attribute__((address_space(1)))
#define LAS __attribute__((address_space(3)))

static __device__ __forceinline__ void gload16(const void* g, u16* l) {
  __builtin_amdgcn_global_load_lds((const GAS u32*)g, (LAS u32*)l, 16, 0, 0);
}

static __device__ __forceinline__ u16 f2bf(float f) {
  u32 u = __float_as_uint(f);
  return (u16)((u + 0x7fffu + ((u >> 16) & 1u)) >> 16);
}
static __device__ __forceinline__ float sigmoid_(float x) {
  return 1.0f / (1.0f + __expf(-x));
}
static __device__ __forceinline__ float gelu_(float x) {
  // jax.nn.gelu tanh-approx: x*sigmoid(2*0.79788456*(x+0.044715x^3))
  const float t3 = x * x * x;
  return x / (1.0f + __expf(-1.5957691216057308f * fmaf(0.044715f, t3, x)));
}

// x (B,L,H) -> h (B,H,L)
__global__ __launch_bounds__(256) void k_transpose_in(const float* __restrict__ x,
                                                      float* __restrict__ h) {
  __shared__ float t[64][65];
  const int b = blockIdx.z;
  const int h0 = blockIdx.x * 64;
  const int l0 = blockIdx.y * 64;
  const int c = threadIdx.x & 63;
  const int r0 = threadIdx.x >> 6;
  const float* xp = x + (size_t)b * SEQ * HDIM;
#pragma unroll
  for (int r = r0; r < 64; r += 4)
    t[r][c] = xp[(size_t)(l0 + r) * HDIM + h0 + c];
  __syncthreads();
  float* hp = h + (size_t)b * HDIM * SEQ;
#pragma unroll
  for (int r = r0; r < 64; r += 4)
    hp[(size_t)(h0 + r) * SEQ + l0 + c] = t[c][r];
}

// h (B,H,L) -> out (B,L,H)
__global__ __launch_bounds__(256) void k_transpose_out(const float* __restrict__ h,
                                                       float* __restrict__ o) {
  __shared__ float t[64][65];
  const int b = blockIdx.z;
  const int h0 = blockIdx.x * 64;
  const int l0 = blockIdx.y * 64;
  const int c = threadIdx.x & 63;
  const int r0 = threadIdx.x >> 6;
  const float* hp = h + (size_t)b * HDIM * SEQ;
#pragma unroll
  for (int r = r0; r < 64; r += 4)
    t[r][c] = hp[(size_t)(h0 + r) * SEQ + l0 + c];
  __syncthreads();
  float* op = o + (size_t)b * SEQ * HDIM;
#pragma unroll
  for (int r = r0; r < 64; r += 4)
    op[(size_t)(l0 + r) * HDIM + h0 + c] = t[c][r];
}

// channel LayerNorm over H at each (b,l); h,z in (B,H,L)
__global__ __launch_bounds__(256) void k_ln(const float* __restrict__ h,
                                            float* __restrict__ z,
                                            const float* __restrict__ w,
                                            const float* __restrict__ bb) {
  __shared__ float ps[8][32], ps2[8][32], smu[32], srs[32];
  const int t = threadIdx.x;
  const int hc = t >> 5;
  const int li = t & 31;
  const int p0 = blockIdx.x * 32;
  const int b = p0 >> 10;
  const int l = (p0 & (SEQ - 1)) + li;
  const float* hp = h + (size_t)b * HDIM * SEQ + l;
  float s = 0.f, s2 = 0.f;
  const int h0 = hc * 128;
#pragma unroll 8
  for (int i = 0; i < 128; ++i) {
    float v = hp[(size_t)(h0 + i) * SEQ];
    s += v;
    s2 = fmaf(v, v, s2);
  }
  ps[hc][li] = s;
  ps2[hc][li] = s2;
  __syncthreads();
  if (t < 32) {
    float ss = 0.f, ss2 = 0.f;
#pragma unroll
    for (int c = 0; c < 8; ++c) { ss += ps[c][t]; ss2 += ps2[c][t]; }
    float mu = ss * (1.0f / HDIM);
    float var = ss2 * (1.0f / HDIM) - mu * mu;
    smu[t] = mu;
    srs[t] = 1.0f / sqrtf(var + 1e-5f);
  }
  __syncthreads();
  const float mu = smu[li], rs = srs[li];
  float* zp = z + (size_t)b * HDIM * SEQ + l;
#pragma unroll 8
  for (int i = 0; i < 128; ++i) {
    const int hh = h0 + i;
    float v = hp[(size_t)hh * SEQ];
    zp[(size_t)hh * SEQ] = fmaf((v - mu) * rs, w[hh], bb[hh]);
  }
}

// Chunked diagonal-SSM scan + D_skip + GELU, emitting y as bf16 in (B, L, H).
// Group of 32 lanes per (b,h); lane = 32-step chunk of L. Local recurrence ->
// Kogge-Stone complex prefix scan of chunk states -> final recurrence with
// correct init. Block covers 8 consecutive h of one b; LDS transpose gives
// one uint4 (8 h) store per l.
__global__ __launch_bounds__(256) void k_scan(
    const float* __restrict__ z, u16* __restrict__ yhi,
    const float* __restrict__ log_dt, const float* __restrict__ A_re_log,
    const float* __restrict__ A_im, const float* __restrict__ C_re,
    const float* __restrict__ C_im, const float* __restrict__ D_skip) {
  __shared__ float4 prm[8][32];
  __shared__ float2 p32[8][32];
  __shared__ u32 ybuf[8][1028];
  const int t = threadIdx.x;
  const int g = t >> 5, lane = t & 31;
  const int pair = blockIdx.x * 8 + g;
  const int b = pair >> 10, hh = pair & (HDIM - 1);
  {
    const float dt = expf(log_dt[hh]);
    const int idx = hh * NSTATE + lane;
    const float Are = -expf(A_re_log[idx]);
    const float Aim = A_im[idx];
    const float dre = Are * dt, dim = Aim * dt;
    const float cy = cosf(dim), sy = sinf(dim);
    const float em = expm1f(dre);
    const float ex = em + 1.0f;
    const float er = ex * cy, ei = ex * sy;           // exp(dtA)
    const float em1r = fmaf(em, cy, cy - 1.0f);       // Re expm1(dtA)
    const float em1i = ei;                            // Im expm1(dtA)
    const float den = 1.0f / fmaf(Are, Are, Aim * Aim);
    const float rr = (em1r * Are + em1i * Aim) * den; // expm1(dtA)/A
    const float ri = (em1i * Are - em1r * Aim) * den;
    const float cr = C_re[idx], ci = C_im[idx];
    prm[g][lane] = make_float4(er, ei, 2.0f * (cr * rr - ci * ri),
                               2.0f * (cr * ri + ci * rr));
    float ar = er, ai = ei;                           // e^32 via 5 squarings
#pragma unroll
    for (int q = 0; q < 5; ++q) {
      const float nr = fmaf(ar, ar, -(ai * ai));
      ai = 2.0f * ar * ai;
      ar = nr;
    }
    p32[g][lane] = make_float2(ar, ai);
  }
  __syncthreads();
  const float* zp = z + ((size_t)b * HDIM + hh) * SEQ + lane * 32;
  float zb[32];
#pragma unroll
  for (int i = 0; i < 8; ++i) {
    const float4 v = *(const float4*)(zp + i * 4);
    zb[i * 4] = v.x; zb[i * 4 + 1] = v.y; zb[i * 4 + 2] = v.z; zb[i * 4 + 3] = v.w;
  }
  float ya[32];
#pragma unroll
  for (int j = 0; j < 32; ++j) ya[j] = 0.f;
#pragma unroll 2
  for (int n = 0; n < NSTATE; ++n) {   // unroll-2: interleave 2 indep chains
    const float4 pp = prm[g][n];
    const float er = pp.x, ei = pp.y, Ctr = pp.z, Cti = pp.w;
    const float2 q32 = p32[g][n];
    float sr = 0.f, si = 0.f;
#pragma unroll
    for (int j = 0; j < 32; ++j) {   // local pass (chunk state only)
      const float nr = fmaf(er, sr, fmaf(-ei, si, zb[j]));
      si = fmaf(er, si, ei * sr);
      sr = nr;
    }
    float fr = q32.x, fi = q32.y;    // inclusive Kogge-Stone scan, ratio e^32
#pragma unroll
    for (int d = 1; d < 32; d <<= 1) {
      const float ur = __shfl_up(sr, d, 32);
      const float ui = __shfl_up(si, d, 32);
      if (lane >= d) {
        sr = fmaf(fr, ur, fmaf(-fi, ui, sr));
        si = fmaf(fr, ui, fmaf(fi, ur, si));
      }
      const float nfr = fmaf(fr, fr, -(fi * fi));
      fi = 2.0f * fr * fi;
      fr = nfr;
    }
    float inr = __shfl_up(sr, 1, 32); // exclusive = state entering this chunk
    float ini = __shfl_up(si, 1, 32);
    if (lane == 0) { inr = 0.f; ini = 0.f; }
    sr = inr; si = ini;
#pragma unroll
    for (int j = 0; j < 32; ++j) {   // final pass with correct init + y accum
      const float nr = fmaf(er, sr, fmaf(-ei, si, zb[j]));
      si = fmaf(er, si, ei * sr);
      sr = nr;
      ya[j] = fmaf(Ctr, sr, fmaf(-Cti, si, ya[j]));
    }
  }
  const float D = D_skip[hh];
  // bf16 y, staged with bit-swapped index (conflict-free writes)
#pragma unroll
  for (int j = 0; j < 32; ++j) {
    const float yv = gelu_(fmaf(D, zb[j], ya[j]));
    ybuf[g][(j << 5) | lane] = (u32)f2bf(yv);
  }
  __syncthreads();
  const int b2 = (blockIdx.x * 8) >> 10;
  const int h0 = (blockIdx.x * 8) & (HDIM - 1);
#pragma unroll
  for (int q = 0; q < 4; ++q) {
    const int l = ((t & 31) << 5) + (t >> 5) + 8 * q;
    const int idx = (((t >> 5) + 8 * q) << 5) | (t & 31);
    u32 v[8];
#pragma unroll
    for (int g2 = 0; g2 < 8; ++g2) v[g2] = ybuf[g2][idx];
    uint4 HI;
    HI.x = v[0] | (v[1] << 16);
    HI.y = v[2] | (v[3] << 16);
    HI.z = v[4] | (v[5] << 16);
    HI.w = v[6] | (v[7] << 16);
    *(uint4*)(yhi + ((size_t)b2 * SEQ + l) * HDIM + h0) = HI;
  }
}

// W (2H,H) f32 -> bf16
__global__ __launch_bounds__(256) void k_wsplit(const float* __restrict__ W,
                                                u16* __restrict__ whi) {
  const size_t i = ((size_t)blockIdx.x * 256 + threadIdx.x) * 4;
  const float4 v = *(const float4*)(W + i);
  const float f[4] = {v.x, v.y, v.z, v.w};
  u32 hp[2];
#pragma unroll
  for (int q = 0; q < 2; ++q)
    hp[q] = (u32)f2bf(f[q * 2]) | ((u32)f2bf(f[q * 2 + 1]) << 16);
  *(uint2*)(whi + i) = make_uint2(hp[0], hp[1]);
}

// out = W(2H,H) @ y^T; y in (B,L,H): both operands stage as [row][32k], read
// as contiguous short8. T2 XOR-swizzle (chunk ^= (row>>1)&3) applied
// both-sides: pre-swizzled global source for global_load_lds (linear LDS
// dest) + swizzled ds_read address -> conflict-free b128 reads.
// GLU(out[:H], out[H:]) added into residual h (B,H,L). 128x128 tile, BK=32,
// 4 waves. A rows interleave the GLU halves in 32-row blocks so acc[m] (u0)
// pairs with acc[m+2] (u1) thread-locally.
__global__ __launch_bounds__(256) void k_gemm_glu(
    const u16* __restrict__ yhi, const u16* __restrict__ whi,
    const float* __restrict__ bias, float* __restrict__ h) {
  __shared__ __align__(16) u16 smem[8192];  // A: [0,4096) 128r x 32k; B: [4096,8192)
  const int tid = threadIdx.x;
  const int bb = blockIdx.z;
  const int my = blockIdx.y;
  const int l0 = blockIdx.x * 128;
  const int lane = tid & 63, wid = tid >> 6;
  const int wr = wid & 1, wc = wid >> 1;
  const int l15 = lane & 15, g4 = lane >> 4;

  f32x4 acc[4][4];
#pragma unroll
  for (int m = 0; m < 4; ++m)
#pragma unroll
    for (int n = 0; n < 4; ++n) acc[m][n] = (f32x4){0.f, 0.f, 0.f, 0.f};

  size_t aOff[2], bOff[2];
#pragma unroll
  for (int i = 0; i < 2; ++i) {
    const int CH = tid + 256 * i;
    const int row = CH >> 2;
    // source pre-swizzle: logical chunk for this (linear) LDS slot
    const int ko = ((CH & 3) ^ ((CH >> 3) & 3)) * 8;
    // A: interleave halves in 32-row blocks
    const int gg = row >> 5, rr = row & 31;
    const int grow = (gg & 1) * HDIM + my * 64 + (gg >> 1) * 32 + rr;
    aOff[i] = (size_t)grow * HDIM + ko;
    // B: y (B,L,H): LDS l-row <- global l0+row
    bOff[i] = ((size_t)(bb * SEQ + l0 + row)) * HDIM + ko;
  }
  u16* aDst0 = &smem[wid * 512];
  u16* aDst1 = &smem[wid * 512 + 2048];
  u16* bDst0 = &smem[4096 + wid * 512];
  u16* bDst1 = &smem[4096 + wid * 512 + 2048];

  // swizzled read offsets (u16 units)
  int aRd[4], bRd[4];
#pragma unroll
  for (int m = 0; m < 4; ++m) {
    const int ra = wr * 64 + m * 16 + l15;
    aRd[m] = ra * 32 + (g4 ^ ((ra >> 1) & 3)) * 8;
    const int rb = wc * 64 + m * 16 + l15;
    bRd[m] = 4096 + rb * 32 + (g4 ^ ((rb >> 1) & 3)) * 8;
  }

#pragma unroll 1
  for (int k0 = 0; k0 < HDIM; k0 += 32) {
    __syncthreads();
    gload16(whi + aOff[0] + k0, aDst0);
    gload16(whi + aOff[1] + k0, aDst1);
    gload16(yhi + bOff[0] + k0, bDst0);
    gload16(yhi + bOff[1] + k0, bDst1);
    __syncthreads();
    short8 a[4], bq[4];
#pragma unroll
    for (int m = 0; m < 4; ++m) a[m] = *(const short8*)&smem[aRd[m]];
#pragma unroll
    for (int n = 0; n < 4; ++n) bq[n] = *(const short8*)&smem[bRd[n]];
#pragma unroll
    for (int m = 0; m < 4; ++m)
#pragma unroll
      for (int n = 0; n < 4; ++n)
        acc[m][n] =
            __builtin_amdgcn_mfma_f32_16x16x32_bf16(a[m], bq[n], acc[m][n], 0, 0, 0);
  }

  float* hp = h + (size_t)bb * HDIM * SEQ;
#pragma unroll
  for (int m = 0; m < 2; ++m)
#pragma unroll
    for (int j = 0; j < 4; ++j) {
      const int R = my * 64 + wr * 32 + m * 16 + g4 * 4 + j;
      const float b0 = bias[R], b1 = bias[HDIM + R];
#pragma unroll
      for (int n = 0; n < 4; ++n) {
        const float u0 = acc[m][n][j] + b0;
        const float u1 = acc[m + 2][n][j] + b1;
        const int c = l0 + wc * 64 + n * 16 + l15;
        hp[(size_t)R * SEQ + c] += u0 * sigmoid_(u1);
      }
    }
}

extern "C" void kernel_launch(void* const* d_in, const int* in_sizes, int n_in,
                              void* d_out, int out_size, void* d_ws, size_t ws_size,
                              hipStream_t stream) {
  (void)in_sizes; (void)n_in; (void)out_size; (void)ws_size;
  const float* x        = (const float*)d_in[0];
  const float* ln_w     = (const float*)d_in[1];
  const float* ln_b     = (const float*)d_in[2];
  const float* log_dt   = (const float*)d_in[3];
  const float* A_re_log = (const float*)d_in[4];
  const float* A_im     = (const float*)d_in[5];
  const float* C_re     = (const float*)d_in[6];
  const float* C_im     = (const float*)d_in[7];
  const float* D_skip   = (const float*)d_in[8];
  const float* W_out    = (const float*)d_in[9];
  const float* b_out    = (const float*)d_in[10];

  const size_t NTOK = (size_t)BATCH * HDIM * SEQ;  // 8M
  float* h = (float*)d_ws;                         // 32MB
  float* z = h + NTOK;                             // 32MB (reused for W bf16)
  u16* whi = (u16*)z;                              // overlays z after scan
  u16* yhi = (u16*)d_out;                          // d_out doubles as y buffer

  k_transpose_in<<<dim3(HDIM / 64, SEQ / 64, BATCH), 256, 0, stream>>>(x, h);
  for (int i = 0; i < NLAYERS; ++i) {
    k_ln<<<BATCH * SEQ / 32, 256, 0, stream>>>(h, z, ln_w + i * HDIM, ln_b + i * HDIM);
    k_scan<<<BATCH * HDIM / 8, 256, 0, stream>>>(z, yhi, log_dt + i * HDIM,
        A_re_log + (size_t)i * HDIM * NSTATE, A_im + (size_t)i * HDIM * NSTATE,
        C_re + (size_t)i * HDIM * NSTATE, C_im + (size_t)i * HDIM * NSTATE,
        D_skip + i * HDIM);
    k_wsplit<<<2 * HDIM * HDIM / 1024, 256, 0, stream>>>(
        W_out + (size_t)i * 2 * HDIM * HDIM, whi);
    k_gemm_glu<<<dim3(SEQ / 128, HDIM / 64, BATCH), 256, 0, stream>>>(
        yhi, whi, b_out + (size_t)i * 2 * HDIM, h);
  }
  k_transpose_out<<<dim3(HDIM / 64, SEQ / 64, BATCH), 256, 0, stream>>>(h, (float*)d_out);
}